// Round 7
// baseline (1071.564 us; speedup 1.0000x reference)
//
#include <hip/hip_runtime.h>

// LSTM B=512 T=1024 H=150 I=1 + Linear(150->1) + sigmoid.
// 32 blocks x 512 threads (8 waves, 2/SIMD). Block owns 16 sequences.
// M = 640 virtual rows, vrow = 4*cell+gate (cell-major), 38 MFMA tiles of 16;
//   vrow 600 carries W_out. K = 160: k<150 = h (f16 LDS, double-buffered),
//   k=150 = 1.0 (bias), k=151 = x_t. Weights pre-scaled by -log2e / +2log2e
//   so pointwise = 5 exp2 + 2 rcp per cell.
// ROUND-7 CHANGE: 512 threads + waves_per_eu(2,2) + keep >80KB LDS pad.
//   r3-r6 all reported VGPR_Count 76-84 with ~86 AGPRs (split of the 170-
//   granule 3-waves/EU budget): weight frags sat in AGPRs and every step
//   paid ~80 v_accvgpr_read per wave to feed the MFMA A-operand (~480
//   cyc/SIMD/step), which matches the VALUBusy excess and the invariance
//   of dur to schedule. At 2 waves/EU the budget is 256 granules -> pure
//   arch-VGPR allocation (~170) fits with slack -> copies vanish.
//   Tile ownership: wave w owns {w, 8+w, 16+w, 24+w} + (32+w for w<6).

typedef _Float16 half8 __attribute__((ext_vector_type(8)));
typedef float f32x4 __attribute__((ext_vector_type(4)));

#define LOG2E 1.44269504088896340736f
#define TWOLOG2E 2.88539008177792681472f

__global__
__attribute__((amdgpu_flat_work_group_size(512, 512), amdgpu_waves_per_eu(2, 2)))
void lstm_kernel(
    const float* __restrict__ x,      // [512][1024]
    const float* __restrict__ W_ih,   // [600]
    const float* __restrict__ W_hh,   // [600][150]
    const float* __restrict__ b_ih,   // [600]
    const float* __restrict__ b_hh,   // [600]
    const float* __restrict__ W_out,  // [150]
    const float* __restrict__ b_out,  // [1]
    float* __restrict__ out)          // [512][1024]
{
  const int tid  = threadIdx.x;
  const int wid  = tid >> 6;
  const int lane = tid & 63;
  const int q    = lane >> 4;   // k-subchunk for A/B frags; cell offset for D
  const int b    = lane & 15;   // batch col (B/D); A-frag row m
  const int bid  = blockIdx.x;

  // stride 168 f16 = 336 B
  __shared__ __align__(16) _Float16 hbuf[2][16][168];
  // [16][2700] = 86.4 KB: cols 0-1023 hold x; rest is occupancy padding
  // (forces 1 block/CU so the 2-waves/EU register budget holds at runtime).
  __shared__ _Float16 xlds[16][2700];

  // ---- prologue: zero hbuf, stage x as f16 ----
  for (int i = tid; i < 2*16*168; i += 512)
    (&hbuf[0][0][0])[i] = (_Float16)0.0f;
  {
    const float4* x4 = (const float4*)(x + (size_t)bid * 16 * 1024);
    for (int i = tid; i < 16*256; i += 512) {
      int row = i >> 8, c4 = i & 255;
      float4 v = x4[row*256 + c4];
      xlds[row][c4*4+0] = (_Float16)v.x;
      xlds[row][c4*4+1] = (_Float16)v.y;
      xlds[row][c4*4+2] = (_Float16)v.z;
      xlds[row][c4*4+3] = (_Float16)v.w;
    }
  }
  __syncthreads();
  if (tid < 32) hbuf[tid>>4][tid&15][150] = (_Float16)1.0f;  // bias column
  if (tid < 16) hbuf[0][tid][151] = xlds[tid][0];            // x_0
  __syncthreads();

  // ---- tile ownership: wave w -> {w, 8+w, 16+w, 24+w} + (32+w if w<6) ----
  const int ntl = (wid < 6) ? 5 : 4;
  int tiles[5];
  tiles[0] = wid; tiles[1] = 8 + wid; tiles[2] = 16 + wid;
  tiles[3] = 24 + wid; tiles[4] = 32 + wid;   // used only when ntl==5

  // ---- weight fragments (A operand): up to 5 tiles x 5 K-chunks = 100 VGPR ----
  const float bo = b_out[0];
  half8 wf[5][5];
#pragma unroll
  for (int tl = 0; tl < 5; ++tl) {
#pragma unroll
    for (int s = 0; s < 5; ++s) wf[tl][s] = (half8)(_Float16)0.0f;
    if (tl < ntl) {
      const int tg   = tiles[tl];
      const int vrow = tg*16 + b;     // A-frag: m = lane&15
      const int cell = vrow >> 2, gate = vrow & 3;
      const float alpha = (gate == 2) ? TWOLOG2E : -LOG2E;
#pragma unroll
      for (int s = 0; s < 5; ++s) {
        half8 v;
#pragma unroll
        for (int j = 0; j < 8; ++j) {
          const int k = s*32 + q*8 + j;  // same (q,j)->k map as B frags
          float w = 0.0f;
          if (vrow == 600) {             // out row
            if (k < 150)       w = -LOG2E * W_out[k];
            else if (k == 150) w = -LOG2E * bo;
          } else if (cell < 150) {
            const int orow = gate*150 + cell;
            if (k < 150)       w = alpha * W_hh[orow*150 + k];
            else if (k == 150) w = alpha * (b_ih[orow] + b_hh[orow]);
            else if (k == 151) w = alpha * W_ih[orow];
          }
          v[j] = (_Float16)w;
        }
        wf[tl][s] = v;
      }
    }
  }

  float cst[5] = {0.f, 0.f, 0.f, 0.f, 0.f};
  const bool is_x   = (wid == 7) && (q == 3);
  const bool is_out = (wid == 5) && (q == 2);  // vrow 600 -> tile 37 (tl=4), m=8, reg 0
  float* outp = out + ((size_t)bid*16 + b) * 1024;

  int cur = 0;
  for (int t = 0; t <= 1024; ++t) {
    _Float16 xv = (_Float16)0.0f;
    if (is_x && t < 1023) xv = xlds[b][t+1];   // issued early, used post-pointwise

    half8 bf[5];
#pragma unroll
    for (int s = 0; s < 5; ++s)
      bf[s] = *(const half8*)&hbuf[cur][b][s*32 + q*8];

    f32x4 acc[5];
#pragma unroll
    for (int tl = 0; tl < 5; ++tl) {
      if (tl < ntl) {
        f32x4 a = {0.f, 0.f, 0.f, 0.f};
#pragma unroll
        for (int s = 0; s < 5; ++s)
          a = __builtin_amdgcn_mfma_f32_16x16x32_f16(wf[tl][s], bf[s], a, 0, 0, 0);
        acc[tl] = a;
      }
    }

    // out_{t-1} = sigmoid(Wout.h_{t-1} + b_out); acc pre-scaled by -log2e
    if (is_out && t >= 1)
      outp[t-1] = __builtin_amdgcn_rcpf(1.0f + __builtin_amdgcn_exp2f(acc[4][0]));
    if (t == 1024) break;

    const int nxt = cur ^ 1;
#pragma unroll
    for (int tl = 0; tl < 5; ++tl) {
      if (tl < ntl) {
        const int cellg = tiles[tl]*4 + q;
        // acc regs: 0=i',1=f',2=g',3=o' (pre-scaled preacts)
        const float ei = __builtin_amdgcn_exp2f(acc[tl][0]);
        const float ef = __builtin_amdgcn_exp2f(acc[tl][1]);
        const float eg = __builtin_amdgcn_exp2f(acc[tl][2]);
        const float eo = __builtin_amdgcn_exp2f(acc[tl][3]);
        const float A  = 1.0f + ei;     // 1/i
        const float F  = 1.0f + ef;     // 1/f
        const float G1 = eg + 1.0f;
        const float Gm = eg - 1.0f;     // g = Gm/G1
        const float AG = A * G1;
        const float num = fmaf(cst[tl], AG, Gm * F);     // c*A*G1 + Gm*F
        const float cn  = num * __builtin_amdgcn_rcpf(F * AG);
        cst[tl] = cn;
        const float ec = __builtin_amdgcn_exp2f(TWOLOG2E * cn);
        const float h  = (ec - 1.0f) *
                         __builtin_amdgcn_rcpf((1.0f + eo) * (ec + 1.0f)); // o*tanh(c)
        if (cellg < 150) hbuf[nxt][b][cellg] = (_Float16)h;
      }
    }
    if (is_x && t < 1023) hbuf[nxt][b][151] = xv;  // x_{t+1}
    __syncthreads();
    cur = nxt;
  }
}

extern "C" void kernel_launch(void* const* d_in, const int* in_sizes, int n_in,
                              void* d_out, int out_size, void* d_ws, size_t ws_size,
                              hipStream_t stream) {
  const float* x     = (const float*)d_in[0];
  const float* W_ih  = (const float*)d_in[1];
  const float* W_hh  = (const float*)d_in[2];
  const float* b_ih  = (const float*)d_in[3];
  const float* b_hh  = (const float*)d_in[4];
  const float* W_out = (const float*)d_in[5];
  const float* b_out = (const float*)d_in[6];
  lstm_kernel<<<dim3(32), dim3(512), 0, stream>>>(
      x, W_ih, W_hh, b_ih, b_hh, W_out, b_out, (float*)d_out);
}

// Round 8
// 1069.132 us; speedup vs baseline: 1.0023x; 1.0023x over previous
//
#include <hip/hip_runtime.h>

// LSTM B=512 T=1024 H=150 I=1 + Linear(150->1) + sigmoid.
// 32 blocks x 512 threads (8 waves). Block owns 16 sequences.
// M = 640 virtual rows, vrow = 4*cell+gate (cell-major), 38 tiles of 16 rows;
//   vrow 600 carries W_out. K = 160: k<150 = h (f16 LDS double-buffered),
//   k=150 = 1.0 (bias), k=151 = x_t. Weights pre-scaled by -log2e / +2log2e
//   so pointwise = 5 exp2 + 2 rcp per cell.
// ROUND-8 CHANGE: cell-split software pipeline. r1-r7 proved the wall is the
//   per-step phase convoy (measured 2414 cyc/step == zero-overlap sum of
//   LDS 480 + trans 560 + VALU ~350 + MFMA 240; invariant to waves/VGPR).
//   Split: E = cells 0-63 (K-chunks s0,s1; tiles 0-15), L = cells 64-149 +
//   bias/x (s2-s4; tiles 16-37). Per step: L-read -> L-MFMA -> out ->
//   pointwise-E -> write-E -> barE -> [read-E + E-MFMA of step t+1] ->
//   pointwise-L -> write-L -> barL. Next step's LDS reads + 40% of its MFMAs
//   run in the trans-shadow of pointwise-L. acc ping-pong (accA/accB), loop
//   2-unrolled so all acc/cst indices are static.

typedef _Float16 half8 __attribute__((ext_vector_type(8)));
typedef float f32x4 __attribute__((ext_vector_type(4)));

#define LOG2E 1.44269504088896340736f
#define TWOLOG2E 2.88539008177792681472f

// pointwise cell update for tile slot TL from accumulator ACC, h -> hbuf[NXT]
#define PW(ACC, TL, NXT)                                                     \
  {                                                                          \
    const int cellg = tiles[TL]*4 + q;                                       \
    const float ei = __builtin_amdgcn_exp2f(ACC[TL][0]);                     \
    const float ef = __builtin_amdgcn_exp2f(ACC[TL][1]);                     \
    const float eg = __builtin_amdgcn_exp2f(ACC[TL][2]);                     \
    const float eo = __builtin_amdgcn_exp2f(ACC[TL][3]);                     \
    const float A  = 1.0f + ei;     /* 1/i */                                \
    const float F  = 1.0f + ef;     /* 1/f */                                \
    const float G1 = eg + 1.0f;                                              \
    const float Gm = eg - 1.0f;     /* g = Gm/G1 */                          \
    const float AG = A * G1;                                                 \
    const float num = fmaf(cst[TL], AG, Gm * F);                             \
    const float cn  = num * __builtin_amdgcn_rcpf(F * AG);                   \
    cst[TL] = cn;                                                            \
    const float ec = __builtin_amdgcn_exp2f(TWOLOG2E * cn);                  \
    const float hv = (ec - 1.0f) *                                           \
                     __builtin_amdgcn_rcpf((1.0f + eo) * (ec + 1.0f));       \
    if (cellg < 150) hbuf[NXT][b][cellg] = (_Float16)hv;                     \
  }

// one timestep: ACC = this step's accumulator (E-partials already in),
// ACCN = next step's accumulator (E-partials produced here). CUR/NXT literal.
#define STEP(ACC, ACCN, CUR, NXT, T)                                         \
  {                                                                          \
    _Float16 xv = (_Float16)0.0f;                                            \
    if (is_x && (T) < 1023) xv = xlds[b][(T)+1];                             \
    /* phase 1: read L-chunks of h(t-1) */                                   \
    half8 l2 = *(const half8*)&hbuf[CUR][b][64  + q*8];                      \
    half8 l3 = *(const half8*)&hbuf[CUR][b][96  + q*8];                      \
    half8 l4 = *(const half8*)&hbuf[CUR][b][128 + q*8];                      \
    /* phase 2: finish MFMA for step T */                                    \
    _Pragma("unroll")                                                        \
    for (int tl = 0; tl < 5; ++tl) if (tl < ntl) {                           \
      ACC[tl] = __builtin_amdgcn_mfma_f32_16x16x32_f16(wf[tl][2], l2, ACC[tl], 0,0,0); \
      ACC[tl] = __builtin_amdgcn_mfma_f32_16x16x32_f16(wf[tl][3], l3, ACC[tl], 0,0,0); \
      ACC[tl] = __builtin_amdgcn_mfma_f32_16x16x32_f16(wf[tl][4], l4, ACC[tl], 0,0,0); \
    }                                                                        \
    /* phase 3: out_{T-1} = sigmoid(Wout.h_{T-1}+b) rides tile 37 */         \
    if (is_out && (T) >= 1)                                                  \
      outp[(T)-1] = __builtin_amdgcn_rcpf(1.0f + __builtin_amdgcn_exp2f(ACC[4][0])); \
    /* phase 4: pointwise E tiles (slots 0,1), write E cells of h(T) */      \
    PW(ACC, 0, NXT); PW(ACC, 1, NXT);                                        \
    __syncthreads();  /* barE: E region of h(T) visible */                   \
    /* phase 6: read E of h(T), start step T+1 (runs in trans-shadow) */     \
    {                                                                        \
      half8 e0 = *(const half8*)&hbuf[NXT][b][q*8];                          \
      half8 e1 = *(const half8*)&hbuf[NXT][b][32 + q*8];                     \
      _Pragma("unroll")                                                      \
      for (int tl = 0; tl < 5; ++tl) if (tl < ntl) {                         \
        ACCN[tl] = __builtin_amdgcn_mfma_f32_16x16x32_f16(wf[tl][0], e0, ZERO, 0,0,0); \
        ACCN[tl] = __builtin_amdgcn_mfma_f32_16x16x32_f16(wf[tl][1], e1, ACCN[tl], 0,0,0); \
      }                                                                      \
    }                                                                        \
    /* phase 7: pointwise L tiles (slots 2-4), write L cells of h(T) */      \
    PW(ACC, 2, NXT); PW(ACC, 3, NXT);                                        \
    if (ntl == 5) PW(ACC, 4, NXT);                                           \
    if (is_x && (T) < 1023) hbuf[NXT][b][151] = xv;                          \
    __syncthreads();  /* barL: L region of h(T) visible */                   \
  }

__global__
__attribute__((amdgpu_flat_work_group_size(512, 512), amdgpu_waves_per_eu(2, 2)))
void lstm_kernel(
    const float* __restrict__ x,      // [512][1024]
    const float* __restrict__ W_ih,   // [600]
    const float* __restrict__ W_hh,   // [600][150]
    const float* __restrict__ b_ih,   // [600]
    const float* __restrict__ b_hh,   // [600]
    const float* __restrict__ W_out,  // [150]
    const float* __restrict__ b_out,  // [1]
    float* __restrict__ out)          // [512][1024]
{
  const int tid  = threadIdx.x;
  const int wid  = tid >> 6;
  const int lane = tid & 63;
  const int q    = lane >> 4;   // k-subchunk for A/B frags; cell offset for D
  const int b    = lane & 15;   // batch col (B/D); A-frag row m
  const int bid  = blockIdx.x;

  __shared__ __align__(16) _Float16 hbuf[2][16][168];
  // cols 0-1023 hold x; rest pads LDS >80KB so 1 block/CU (register budget).
  __shared__ _Float16 xlds[16][2700];

  // ---- prologue: zero hbuf, stage x as f16 ----
  for (int i = tid; i < 2*16*168; i += 512)
    (&hbuf[0][0][0])[i] = (_Float16)0.0f;
  {
    const float4* x4 = (const float4*)(x + (size_t)bid * 16 * 1024);
    for (int i = tid; i < 16*256; i += 512) {
      int row = i >> 8, c4 = i & 255;
      float4 v = x4[row*256 + c4];
      xlds[row][c4*4+0] = (_Float16)v.x;
      xlds[row][c4*4+1] = (_Float16)v.y;
      xlds[row][c4*4+2] = (_Float16)v.z;
      xlds[row][c4*4+3] = (_Float16)v.w;
    }
  }
  __syncthreads();
  if (tid < 32) hbuf[tid>>4][tid&15][150] = (_Float16)1.0f;  // bias column
  if (tid < 16) hbuf[0][tid][151] = xlds[tid][0];            // x_0
  __syncthreads();

  // ---- tile ownership: wave w -> {w, 8+w | E} + {16+w, 24+w, (32+w) | L} ----
  const int ntl = (wid < 6) ? 5 : 4;
  int tiles[5];
  tiles[0] = wid; tiles[1] = 8 + wid;
  tiles[2] = 16 + wid; tiles[3] = 24 + wid; tiles[4] = 32 + wid;

  // ---- weight fragments (A operand): up to 5 tiles x 5 K-chunks ----
  const float bo = b_out[0];
  half8 wf[5][5];
#pragma unroll
  for (int tl = 0; tl < 5; ++tl) {
#pragma unroll
    for (int s = 0; s < 5; ++s) wf[tl][s] = (half8)(_Float16)0.0f;
    if (tl < ntl) {
      const int tg   = tiles[tl];
      const int vrow = tg*16 + b;     // A-frag: m = lane&15
      const int cell = vrow >> 2, gate = vrow & 3;
      const float alpha = (gate == 2) ? TWOLOG2E : -LOG2E;
#pragma unroll
      for (int s = 0; s < 5; ++s) {
        half8 v;
#pragma unroll
        for (int j = 0; j < 8; ++j) {
          const int k = s*32 + q*8 + j;  // same (q,j)->k map as B frags
          float w = 0.0f;
          if (vrow == 600) {             // out row
            if (k < 150)       w = -LOG2E * W_out[k];
            else if (k == 150) w = -LOG2E * bo;
          } else if (cell < 150) {
            const int orow = gate*150 + cell;
            if (k < 150)       w = alpha * W_hh[orow*150 + k];
            else if (k == 150) w = alpha * (b_ih[orow] + b_hh[orow]);
            else if (k == 151) w = alpha * W_ih[orow];
          }
          v[j] = (_Float16)w;
        }
        wf[tl][s] = v;
      }
    }
  }

  float cst[5] = {0.f, 0.f, 0.f, 0.f, 0.f};
  const bool is_x   = (wid == 7) && (q == 3);
  const bool is_out = (wid == 5) && (q == 2);  // vrow 600 -> tile 37 (slot 4), reg 0
  float* outp = out + ((size_t)bid*16 + b) * 1024;
  const f32x4 ZERO = {0.f, 0.f, 0.f, 0.f};

  // ---- prime: E-partials for step 0 (h(-1) E-cells are zero) ----
  f32x4 accA[5], accB[5];
  {
    half8 e0 = *(const half8*)&hbuf[0][b][q*8];
    half8 e1 = *(const half8*)&hbuf[0][b][32 + q*8];
#pragma unroll
    for (int tl = 0; tl < 5; ++tl) if (tl < ntl) {
      accA[tl] = __builtin_amdgcn_mfma_f32_16x16x32_f16(wf[tl][0], e0, ZERO, 0,0,0);
      accA[tl] = __builtin_amdgcn_mfma_f32_16x16x32_f16(wf[tl][1], e1, accA[tl], 0,0,0);
    }
  }

  for (int t = 0; t < 1024; t += 2) {
    STEP(accA, accB, 0, 1, t);
    STEP(accB, accA, 1, 0, t + 1);
  }

  // ---- tail: "step 1024" L-MFMA for the out row only -> out[1023] ----
  if (wid == 5) {
    half8 l2 = *(const half8*)&hbuf[0][b][64  + q*8];
    half8 l3 = *(const half8*)&hbuf[0][b][96  + q*8];
    half8 l4 = *(const half8*)&hbuf[0][b][128 + q*8];
    accA[4] = __builtin_amdgcn_mfma_f32_16x16x32_f16(wf[4][2], l2, accA[4], 0,0,0);
    accA[4] = __builtin_amdgcn_mfma_f32_16x16x32_f16(wf[4][3], l3, accA[4], 0,0,0);
    accA[4] = __builtin_amdgcn_mfma_f32_16x16x32_f16(wf[4][4], l4, accA[4], 0,0,0);
    if (is_out)
      outp[1023] = __builtin_amdgcn_rcpf(1.0f + __builtin_amdgcn_exp2f(accA[4][0]));
  }
}

extern "C" void kernel_launch(void* const* d_in, const int* in_sizes, int n_in,
                              void* d_out, int out_size, void* d_ws, size_t ws_size,
                              hipStream_t stream) {
  const float* x     = (const float*)d_in[0];
  const float* W_ih  = (const float*)d_in[1];
  const float* W_hh  = (const float*)d_in[2];
  const float* b_ih  = (const float*)d_in[3];
  const float* b_hh  = (const float*)d_in[4];
  const float* W_out = (const float*)d_in[5];
  const float* b_out = (const float*)d_in[6];
  lstm_kernel<<<dim3(32), dim3(512), 0, stream>>>(
      x, W_ih, W_hh, b_ih, b_hh, W_out, b_out, (float*)d_out);
}